// Round 1
// baseline (454.067 us; speedup 1.0000x reference)
//
#include <hip/hip_runtime.h>
#include <hip/hip_bf16.h>

#define CN 1024
#define BN 256

typedef __attribute__((ext_vector_type(4))) float f32x4;
typedef __attribute__((ext_vector_type(8))) short bf16x8;

__device__ __forceinline__ short f2bf(float f) {
    __hip_bfloat16 h = __float2bfloat16(f);
    return *reinterpret_cast<short*>(&h);
}
__device__ __forceinline__ float sigm(float x) {
    return __builtin_amdgcn_rcpf(1.f + __expf(-x));
}
__device__ __forceinline__ float tanh_fast(float x) {
    return 1.f - 2.f * __builtin_amdgcn_rcpf(1.f + __expf(2.f * x));
}

// ---------------- prep kernel: repack weights + tables into ws ----------------
// block roles: [0,96) repack frag tiles; 96 bias table; [97, 97+1025) per-c emb terms;
// [1122, 1122+256) per-b tables.
__global__ void gkt_prep(
    const int* __restrict__ xt, const int* __restrict__ qt,
    const float* __restrict__ ht, const float* __restrict__ emb_x,
    const float* __restrict__ emb_c,
    const float* __restrict__ fs_W1, const float* __restrict__ fs_b1,
    const float* __restrict__ fs_W2, const float* __restrict__ fs_b2,
    const float* __restrict__ fn0_W1, const float* __restrict__ fn0_b1,
    const float* __restrict__ fn0_W2, const float* __restrict__ fn0_b2,
    const float* __restrict__ fn1_W1, const float* __restrict__ fn1_b1,
    const float* __restrict__ fn1_W2, const float* __restrict__ fn1_b2,
    const float* __restrict__ erase_W, const float* __restrict__ erase_b,
    const float* __restrict__ add_W, const float* __restrict__ add_b,
    const float* __restrict__ gru_Wih, const float* __restrict__ gru_bih,
    const float* __restrict__ gru_Whh, const float* __restrict__ gru_bhh,
    short* __restrict__ wrepack, float* __restrict__ biasc,
    float* __restrict__ ce0, float* __restrict__ ce1,
    float* __restrict__ perb, int* __restrict__ qtsA, int* __restrict__ maskA)
{
    int bid = blockIdx.x;
    int lane = threadIdx.x;
    if (bid < 96) {
        // weight fragment repack. concatenated B matrix (64 x 768) columns:
        // [0,64) A0=fn0_W1[128:192]  [64,128) A1=fn1_W1[128:192]  [128,320) Whh
        // [320,384) fn0_W2  [384,448) fn1_W2  [448,512) erase_W  [512,576) add_W
        // [576,768) Wih
        int t = bid >> 1, kh = bid & 1;
        int colg = t * 16 + (lane & 15);
        int k0 = kh * 32 + (lane >> 4) * 8;
        short v8[8];
#pragma unroll
        for (int j = 0; j < 8; ++j) {
            int k = k0 + j;
            float v;
            if (colg < 64)       v = fn0_W1[(128 + k) * 64 + colg];
            else if (colg < 128) v = fn1_W1[(128 + k) * 64 + (colg - 64)];
            else if (colg < 320) v = gru_Whh[k * 192 + (colg - 128)];
            else if (colg < 384) v = fn0_W2[k * 64 + (colg - 320)];
            else if (colg < 448) v = fn1_W2[k * 64 + (colg - 384)];
            else if (colg < 512) v = erase_W[k * 64 + (colg - 448)];
            else if (colg < 576) v = add_W[k * 64 + (colg - 512)];
            else                 v = gru_Wih[k * 192 + (colg - 576)];
            v8[j] = f2bf(v);
        }
        short* dst = wrepack + ((size_t)(t * 2 + kh) * 64 + lane) * 8;
#pragma unroll
        for (int j = 0; j < 8; ++j) dst[j] = v8[j];
    } else if (bid == 96) {
        for (int g = lane; g < 768; g += 64) {
            float v;
            if (g < 64)       v = fn0_b1[g];
            else if (g < 128) v = fn1_b1[g - 64];
            else if (g < 320) v = gru_bhh[g - 128];
            else if (g < 384) v = fn0_b2[g - 320];
            else if (g < 448) v = fn1_b2[g - 384];
            else if (g < 512) v = erase_b[g - 448];
            else if (g < 576) v = add_b[g - 512];
            else              v = gru_bih[g - 576];
            biasc[g] = v;
        }
    } else if (bid < 97 + CN + 1) {
        int c = bid - 97;
        float e = emb_c[c * 64 + lane];
        float a0 = 0.f, a1 = 0.f;
        for (int k = 0; k < 64; ++k) {
            float ek = __shfl(e, k);
            a0 += ek * fn0_W1[(192 + k) * 64 + lane];
            a1 += ek * fn1_W1[(192 + k) * 64 + lane];
        }
        ce0[c * 64 + lane] = a0;
        ce1[c * 64 + lane] = a1;
    } else {
        int b = bid - (97 + CN + 1);
        int qv = qt[b];
        int mk = (qv != -1);
        int qs = min(max(qv, 0), CN - 1);
        float cq = mk ? emb_x[(size_t)xt[b] * 64 + lane]
                      : emb_c[(size_t)CN * 64 + lane];
        float hl = ht[((size_t)b * CN + qs) * 64 + lane];
        float p0 = 0.f, p1 = 0.f, r0 = 0.f, r1 = 0.f, fs = 0.f;
        for (int k = 0; k < 64; ++k) {
            float hk = __shfl(hl, k), ck = __shfl(cq, k);
            p0 += hk * fn0_W1[k * 64 + lane] + ck * fn0_W1[(64 + k) * 64 + lane];
            p1 += hk * fn1_W1[k * 64 + lane] + ck * fn1_W1[(64 + k) * 64 + lane];
            r0 += ck * fn0_W1[(192 + k) * 64 + lane];
            r1 += ck * fn1_W1[(192 + k) * 64 + lane];
            fs += hk * fs_W1[k * 64 + lane] + ck * fs_W1[(64 + k) * 64 + lane];
        }
        float t1 = fmaxf(fs + fs_b1[lane], 0.f);
        float sf = 0.f;
        for (int k = 0; k < 64; ++k) sf += __shfl(t1, k) * fs_W2[k * 64 + lane];
        sf = fmaxf(sf + fs_b2[lane], 0.f);
        float* pd = perb + (size_t)b * 320;
        pd[lane] = p0; pd[64 + lane] = p1; pd[128 + lane] = r0;
        pd[192 + lane] = r1; pd[256 + lane] = sf;
        if (lane == 0) { qtsA[b] = qs; maskA[b] = mk; }
    }
}

// ---------------- main fused kernel ----------------
#define MFMA(a, bf, c) __builtin_amdgcn_mfma_f32_16x16x32_bf16((a), (bf), (c), 0, 0, 0)
#define LDSFENCE() asm volatile("s_waitcnt lgkmcnt(0)" ::: "memory")

__global__ __launch_bounds__(256) void gkt_main(
    const float* __restrict__ ht, const float* __restrict__ graph,
    const float* __restrict__ ea_w, const float* __restrict__ pred_W,
    const float* __restrict__ pred_b,
    const short* __restrict__ wrepack, const float* __restrict__ biasc,
    const float* __restrict__ ce0g, const float* __restrict__ ce1g,
    const float* __restrict__ perb, const int* __restrict__ qtsA,
    const int* __restrict__ maskA, float* __restrict__ out)
{
    __shared__ float s_h[4][16][68];   // f32 h tile per wave (padded: 68%32=4 -> bank spread)
    __shared__ short s_x0[4][16][72];  // bf16 x0 / m tile
    __shared__ short s_x1[4][16][72];  // bf16 x1 / m' tile
    __shared__ float s_bias[768];
    __shared__ float s_pre0[64], s_pre1[64], s_rw0[64], s_rw1[64], s_sf[64];

    int tid = threadIdx.x;
    int lane = tid & 63, w = tid >> 6;
    int l15 = lane & 15, q = lane >> 4;
    int bid = blockIdx.x;
    int b = bid >> 2, cb = (bid & 3) << 8;

    for (int i = tid; i < 768; i += 256) s_bias[i] = biasc[i];
    if (tid < 64) {
        const float* pd = perb + (size_t)b * 320;
        s_pre0[tid] = pd[tid];       s_pre1[tid] = pd[64 + tid];
        s_rw0[tid]  = pd[128 + tid]; s_rw1[tid]  = pd[192 + tid];
        s_sf[tid]   = pd[256 + tid];
    }
    int qts = qtsA[b];
    int mk  = maskA[b];
    __syncthreads();

    float pw[4];
#pragma unroll
    for (int t = 0; t < 4; ++t) pw[t] = pred_W[t * 16 + l15];
    float pb0 = pred_b[0];

    const bf16x8* WF = (const bf16x8*)wrepack;
    f32x4 zero4 = {0.f, 0.f, 0.f, 0.f};

    for (int rt = 0; rt < 4; ++rt) {
        int c0 = cb + w * 64 + rt * 16;
        const float* hp = ht + ((size_t)(b * CN + c0 + l15)) * 64 + q * 16;
        f32x4 hv0 = *(const f32x4*)hp;
        f32x4 hv1 = *(const f32x4*)(hp + 4);
        f32x4 hv2 = *(const f32x4*)(hp + 8);
        f32x4 hv3 = *(const f32x4*)(hp + 12);

        if (!mk) {
            // h_next == ht row; y = h.predW + pb, no sigmoid
            float part = 0.f;
#pragma unroll
            for (int i = 0; i < 4; ++i)
                part += hv0[i] * pred_W[q * 16 + i] + hv1[i] * pred_W[q * 16 + 4 + i]
                      + hv2[i] * pred_W[q * 16 + 8 + i] + hv3[i] * pred_W[q * 16 + 12 + i];
            part += __shfl_xor(part, 16);
            part += __shfl_xor(part, 32);
            if (q == 0) out[(size_t)b * CN + c0 + l15] = part + pb0;
            continue;
        }

        // wait for previous row-tile's LDS reads before overwriting buffers
        LDSFENCE();
        *(f32x4*)&s_h[w][l15][q * 16]      = hv0;
        *(f32x4*)&s_h[w][l15][q * 16 + 4]  = hv1;
        *(f32x4*)&s_h[w][l15][q * 16 + 8]  = hv2;
        *(f32x4*)&s_h[w][l15][q * 16 + 12] = hv3;

        // per-row scalars (prefetch early)
        float adjv[4], radjv[4], eav[4];
#pragma unroll
        for (int r = 0; r < 4; ++r) {
            int cr = c0 + q * 4 + r;
            adjv[r]  = graph[(size_t)qts * CN + cr];
            radjv[r] = graph[(size_t)cr * CN + qts];
            eav[r]   = ea_w[cr];
        }
        LDSFENCE();

        // h A-fragments (k mapping: k = q*8 + j (+32 for second half) -- matches repack)
        bf16x8 hA0, hA1;
        {
            const float* p0 = &s_h[w][l15][q * 8];
            const float* p1 = &s_h[w][l15][q * 8 + 32];
            f32x4 u0 = *(const f32x4*)p0, u1 = *(const f32x4*)(p0 + 4);
            f32x4 v0 = *(const f32x4*)p1, v1 = *(const f32x4*)(p1 + 4);
#pragma unroll
            for (int j = 0; j < 4; ++j) {
                hA0[j] = f2bf(u0[j]); hA0[4 + j] = f2bf(u1[j]);
                hA1[j] = f2bf(v0[j]); hA1[4 + j] = f2bf(v1[j]);
            }
        }

        // ---- stage 1a: x0 = relu(h@A0 + pre0 + ce0 + b1), x1 likewise ----
#pragma unroll
        for (int t = 0; t < 8; ++t) {
            f32x4 acc = MFMA(hA0, WF[(t * 2 + 0) * 64 + lane], zero4);
            acc = MFMA(hA1, WF[(t * 2 + 1) * 64 + lane], acc);
            int jl = (t & 3) * 16 + l15;
            int jg = t * 16 + l15;
            float base = s_bias[jg] + ((t < 4) ? s_pre0[jl] : s_pre1[jl]);
            const float* cet = (t < 4) ? ce0g : ce1g;
            const float* rwt = (t < 4) ? s_rw0 : s_rw1;
#pragma unroll
            for (int r = 0; r < 4; ++r) {
                int cr = c0 + q * 4 + r;
                float ce = (cr == qts) ? rwt[jl] : cet[(size_t)cr * 64 + jl];
                float u = fmaxf(acc[r] + base + ce, 0.f);
                if (t < 4) s_x0[w][q * 4 + r][jl] = f2bf(u);
                else       s_x1[w][q * 4 + r][jl] = f2bf(u);
            }
        }
        LDSFENCE();

        // ---- stage 2: f0/f1, m = adj*f0 + radj*f1 (override at c==qts) ----
        bf16x8 x0A0 = *(const bf16x8*)&s_x0[w][l15][q * 8];
        bf16x8 x0A1 = *(const bf16x8*)&s_x0[w][l15][q * 8 + 32];
        bf16x8 x1A0 = *(const bf16x8*)&s_x1[w][l15][q * 8];
        bf16x8 x1A1 = *(const bf16x8*)&s_x1[w][l15][q * 8 + 32];
        LDSFENCE();
        float mreg[4][4];
#pragma unroll
        for (int t = 0; t < 4; ++t) {
            f32x4 f0a = MFMA(x0A0, WF[((20 + t) * 2 + 0) * 64 + lane], zero4);
            f0a = MFMA(x0A1, WF[((20 + t) * 2 + 1) * 64 + lane], f0a);
            f32x4 f1a = MFMA(x1A0, WF[((24 + t) * 2 + 0) * 64 + lane], zero4);
            f1a = MFMA(x1A1, WF[((24 + t) * 2 + 1) * 64 + lane], f1a);
            int jl = t * 16 + l15;
            float b0 = s_bias[320 + jl], b1 = s_bias[384 + jl];
#pragma unroll
            for (int r = 0; r < 4; ++r) {
                int cr = c0 + q * 4 + r;
                float f0 = fmaxf(f0a[r] + b0, 0.f), f1 = fmaxf(f1a[r] + b1, 0.f);
                float mv = adjv[r] * f0 + radjv[r] * f1;
                if (cr == qts) mv = s_sf[jl];
                mreg[t][r] = mv;
            }
        }
#pragma unroll
        for (int t = 0; t < 4; ++t)
#pragma unroll
            for (int r = 0; r < 4; ++r)
                s_x0[w][q * 4 + r][t * 16 + l15] = f2bf(mreg[t][r]);
        LDSFENCE();

        // ---- stage 3: erase/add gates, m' = m - w*e*m + w*a ----
        bf16x8 mA0 = *(const bf16x8*)&s_x0[w][l15][q * 8];
        bf16x8 mA1 = *(const bf16x8*)&s_x0[w][l15][q * 8 + 32];
        LDSFENCE();
#pragma unroll
        for (int t = 0; t < 4; ++t) {
            f32x4 eacc = MFMA(mA0, WF[((28 + t) * 2 + 0) * 64 + lane], zero4);
            eacc = MFMA(mA1, WF[((28 + t) * 2 + 1) * 64 + lane], eacc);
            f32x4 aacc = MFMA(mA0, WF[((32 + t) * 2 + 0) * 64 + lane], zero4);
            aacc = MFMA(mA1, WF[((32 + t) * 2 + 1) * 64 + lane], aacc);
            int jl = t * 16 + l15;
            float be = s_bias[448 + jl], ba = s_bias[512 + jl];
#pragma unroll
            for (int r = 0; r < 4; ++r) {
                float eg = sigm(eacc[r] + be);
                float af = tanh_fast(aacc[r] + ba);
                float mp = mreg[t][r] * (1.f - eav[r] * eg) + eav[r] * af;
                s_x1[w][q * 4 + r][jl] = f2bf(mp);
            }
        }
        LDSFENCE();

        // ---- stage 4 + 1b + GRU ----
        bf16x8 mpA0 = *(const bf16x8*)&s_x1[w][l15][q * 8];
        bf16x8 mpA1 = *(const bf16x8*)&s_x1[w][l15][q * 8 + 32];
        LDSFENCE();
        float rg[4][4], ng[4][4];
#pragma unroll
        for (int t = 0; t < 4; ++t) { // r-gate: gi cols [0,64), gh cols [0,64)
            f32x4 gi = MFMA(mpA0, WF[((36 + t) * 2 + 0) * 64 + lane], zero4);
            gi = MFMA(mpA1, WF[((36 + t) * 2 + 1) * 64 + lane], gi);
            f32x4 gh = MFMA(hA0, WF[((8 + t) * 2 + 0) * 64 + lane], zero4);
            gh = MFMA(hA1, WF[((8 + t) * 2 + 1) * 64 + lane], gh);
            int jl = t * 16 + l15;
            float bi = s_bias[576 + jl], bh = s_bias[128 + jl];
#pragma unroll
            for (int r = 0; r < 4; ++r)
                rg[t][r] = sigm(gi[r] + bi + gh[r] + bh);
        }
#pragma unroll
        for (int t = 0; t < 4; ++t) { // n-gate: cols [128,192)
            f32x4 gi = MFMA(mpA0, WF[((44 + t) * 2 + 0) * 64 + lane], zero4);
            gi = MFMA(mpA1, WF[((44 + t) * 2 + 1) * 64 + lane], gi);
            f32x4 gh = MFMA(hA0, WF[((16 + t) * 2 + 0) * 64 + lane], zero4);
            gh = MFMA(hA1, WF[((16 + t) * 2 + 1) * 64 + lane], gh);
            int jl = t * 16 + l15;
            float bi = s_bias[576 + 128 + jl], bh = s_bias[256 + jl];
#pragma unroll
            for (int r = 0; r < 4; ++r)
                ng[t][r] = tanh_fast(gi[r] + bi + rg[t][r] * (gh[r] + bh));
        }
        float yp[4] = {0.f, 0.f, 0.f, 0.f};
#pragma unroll
        for (int t = 0; t < 4; ++t) { // z-gate: cols [64,128); hn & y partial
            f32x4 gi = MFMA(mpA0, WF[((40 + t) * 2 + 0) * 64 + lane], zero4);
            gi = MFMA(mpA1, WF[((40 + t) * 2 + 1) * 64 + lane], gi);
            f32x4 gh = MFMA(hA0, WF[((12 + t) * 2 + 0) * 64 + lane], zero4);
            gh = MFMA(hA1, WF[((12 + t) * 2 + 1) * 64 + lane], gh);
            int jl = t * 16 + l15;
            float bi = s_bias[576 + 64 + jl], bh = s_bias[192 + jl];
#pragma unroll
            for (int r = 0; r < 4; ++r) {
                float z = sigm(gi[r] + bi + gh[r] + bh);
                float hval = s_h[w][q * 4 + r][t * 16 + l15];
                float hn = (1.f - z) * ng[t][r] + z * hval;
                yp[r] += hn * pw[t];
            }
        }
#pragma unroll
        for (int r = 0; r < 4; ++r) {
            float v = yp[r];
            v += __shfl_xor(v, 1);
            v += __shfl_xor(v, 2);
            v += __shfl_xor(v, 4);
            v += __shfl_xor(v, 8);
            if (l15 == 0) out[(size_t)b * CN + c0 + q * 4 + r] = sigm(v + pb0);
        }
    }
}

extern "C" void kernel_launch(void* const* d_in, const int* in_sizes, int n_in,
                              void* d_out, int out_size, void* d_ws, size_t ws_size,
                              hipStream_t stream) {
    (void)in_sizes; (void)n_in; (void)out_size; (void)ws_size;
    const int*   xt      = (const int*)d_in[0];
    const int*   qt      = (const int*)d_in[1];
    const float* ht      = (const float*)d_in[2];
    const float* graph   = (const float*)d_in[3];
    const float* emb_x   = (const float*)d_in[4];
    const float* emb_c   = (const float*)d_in[5];
    const float* fs_W1   = (const float*)d_in[6];
    const float* fs_b1   = (const float*)d_in[7];
    const float* fs_W2   = (const float*)d_in[8];
    const float* fs_b2   = (const float*)d_in[9];
    const float* fn0_W1  = (const float*)d_in[10];
    const float* fn0_b1  = (const float*)d_in[11];
    const float* fn0_W2  = (const float*)d_in[12];
    const float* fn0_b2  = (const float*)d_in[13];
    const float* fn1_W1  = (const float*)d_in[14];
    const float* fn1_b1  = (const float*)d_in[15];
    const float* fn1_W2  = (const float*)d_in[16];
    const float* fn1_b2  = (const float*)d_in[17];
    const float* ea_w    = (const float*)d_in[18];
    const float* erase_W = (const float*)d_in[19];
    const float* erase_b = (const float*)d_in[20];
    const float* add_W   = (const float*)d_in[21];
    const float* add_b   = (const float*)d_in[22];
    const float* gru_Wih = (const float*)d_in[23];
    const float* gru_bih = (const float*)d_in[24];
    const float* gru_Whh = (const float*)d_in[25];
    const float* gru_bhh = (const float*)d_in[26];
    const float* pred_W  = (const float*)d_in[27];
    const float* pred_b  = (const float*)d_in[28];

    char* ws = (char*)d_ws;
    short* wrepack = (short*)(ws);            // 98304 B
    float* biasc   = (float*)(ws + 98304);    // 3072 B
    float* ce0     = (float*)(ws + 102400);   // 262400 B
    float* ce1     = (float*)(ws + 364800);   // 262400 B
    float* perb    = (float*)(ws + 627200);   // 327680 B
    int*   qtsA    = (int*)(ws + 954880);     // 1024 B
    int*   maskA   = (int*)(ws + 955904);     // 1024 B

    gkt_prep<<<96 + 1 + (CN + 1) + BN, 64, 0, stream>>>(
        xt, qt, ht, emb_x, emb_c,
        fs_W1, fs_b1, fs_W2, fs_b2,
        fn0_W1, fn0_b1, fn0_W2, fn0_b2,
        fn1_W1, fn1_b1, fn1_W2, fn1_b2,
        erase_W, erase_b, add_W, add_b,
        gru_Wih, gru_bih, gru_Whh, gru_bhh,
        wrepack, biasc, ce0, ce1, perb, qtsA, maskA);

    gkt_main<<<BN * 4, 256, 0, stream>>>(
        ht, graph, ea_w, pred_W, pred_b,
        wrepack, biasc, ce0, ce1, perb, qtsA, maskA, (float*)d_out);
}

// Round 2
// 283.767 us; speedup vs baseline: 1.6001x; 1.6001x over previous
//
#include <hip/hip_runtime.h>
#include <hip/hip_bf16.h>

#define CN 1024
#define BN 256
#define SMEM_BYTES 130304

typedef __attribute__((ext_vector_type(4))) float f32x4;
typedef __attribute__((ext_vector_type(8))) short bf16x8;

__device__ __forceinline__ short f2bf(float f) {
    __hip_bfloat16 h = __float2bfloat16(f);
    return *reinterpret_cast<short*>(&h);
}
__device__ __forceinline__ float bf2f(short u) {
    union { unsigned int i; float f; } v;
    v.i = ((unsigned int)(unsigned short)u) << 16;
    return v.f;
}
__device__ __forceinline__ float sigm(float x) {
    return __builtin_amdgcn_rcpf(1.f + __expf(-x));
}
__device__ __forceinline__ float tanh_fast(float x) {
    return 1.f - 2.f * __builtin_amdgcn_rcpf(1.f + __expf(2.f * x));
}

// ---------------- prep kernel ----------------
// blocks [0,12): weight repack (wave per col-tile). block 12: bias concat.
// blocks [13,78): ce0/ce1 tables. blocks [78,142): per-b tables (wave per b).
__global__ __launch_bounds__(256) void gkt_prep(
    const int* __restrict__ xt, const int* __restrict__ qt,
    const float* __restrict__ ht, const float* __restrict__ emb_x,
    const float* __restrict__ emb_c,
    const float* __restrict__ fs_W1, const float* __restrict__ fs_b1,
    const float* __restrict__ fs_W2, const float* __restrict__ fs_b2,
    const float* __restrict__ fn0_W1, const float* __restrict__ fn0_b1,
    const float* __restrict__ fn0_W2, const float* __restrict__ fn0_b2,
    const float* __restrict__ fn1_W1, const float* __restrict__ fn1_b1,
    const float* __restrict__ fn1_W2, const float* __restrict__ fn1_b2,
    const float* __restrict__ erase_W, const float* __restrict__ erase_b,
    const float* __restrict__ add_W, const float* __restrict__ add_b,
    const float* __restrict__ gru_Wih, const float* __restrict__ gru_bih,
    const float* __restrict__ gru_Whh, const float* __restrict__ gru_bhh,
    short* __restrict__ wrepack, float* __restrict__ biasc,
    float* __restrict__ ce0, float* __restrict__ ce1,
    float* __restrict__ perb, int* __restrict__ qtsA, int* __restrict__ maskA)
{
    int bid = blockIdx.x;
    int tid = threadIdx.x;
    int lane = tid & 63, wv = tid >> 6;
    __shared__ float inp[4][128];
    __shared__ float t1s[4][64];

    if (bid < 12) {
        // concat B matrix (64 x 768) col-tiles; tile t = bid*4 + wv in [0,48)
        int t = bid * 4 + wv;
        int colg = t * 16 + (lane & 15);
#pragma unroll
        for (int kh = 0; kh < 2; ++kh) {
            int k0 = kh * 32 + (lane >> 4) * 8;
            short v8[8];
#pragma unroll
            for (int j = 0; j < 8; ++j) {
                int k = k0 + j;
                float v;
                if (colg < 64)       v = fn0_W1[(128 + k) * 64 + colg];
                else if (colg < 128) v = fn1_W1[(128 + k) * 64 + (colg - 64)];
                else if (colg < 320) v = gru_Whh[k * 192 + (colg - 128)];
                else if (colg < 384) v = fn0_W2[k * 64 + (colg - 320)];
                else if (colg < 448) v = fn1_W2[k * 64 + (colg - 384)];
                else if (colg < 512) v = erase_W[k * 64 + (colg - 448)];
                else if (colg < 576) v = add_W[k * 64 + (colg - 512)];
                else                 v = gru_Wih[k * 192 + (colg - 576)];
                v8[j] = f2bf(v);
            }
            short* dst = wrepack + ((size_t)(t * 2 + kh) * 64 + lane) * 8;
#pragma unroll
            for (int j = 0; j < 8; ++j) dst[j] = v8[j];
        }
    } else if (bid == 12) {
        for (int g = tid; g < 768; g += 256) {
            float v;
            if (g < 64)       v = fn0_b1[g];
            else if (g < 128) v = fn1_b1[g - 64];
            else if (g < 320) v = gru_bhh[g - 128];
            else if (g < 384) v = fn0_b2[g - 320];
            else if (g < 448) v = fn1_b2[g - 384];
            else if (g < 512) v = erase_b[g - 448];
            else if (g < 576) v = add_b[g - 512];
            else              v = gru_bih[g - 576];
            biasc[g] = v;
        }
    } else if (bid < 78) {
        int cbase = (bid - 13) * 16;
        int j = lane;
#pragma unroll
        for (int p = 0; p < 4; ++p) {
            int c = cbase + p * 4 + wv;
            if (c <= CN) {
                float a0 = 0.f, a1 = 0.f;
                for (int k = 0; k < 64; ++k) {
                    float ek = emb_c[c * 64 + k];
                    a0 += ek * fn0_W1[(192 + k) * 64 + j];
                    a1 += ek * fn1_W1[(192 + k) * 64 + j];
                }
                ce0[c * 64 + j] = a0;
                ce1[c * 64 + j] = a1;
            }
        }
    } else {
        int b = (bid - 78) * 4 + wv;
        int qv = qt[b];
        int mki = (qv != -1);
        int qs = min(max(qv, 0), CN - 1);
        float cq = mki ? emb_x[(size_t)xt[b] * 64 + lane]
                       : emb_c[(size_t)CN * 64 + lane];
        inp[wv][lane]      = ht[((size_t)b * CN + qs) * 64 + lane];
        inp[wv][64 + lane] = cq;
        float p0 = 0.f, p1 = 0.f, fs = 0.f;
        for (int k = 0; k < 128; ++k) {
            float xk = inp[wv][k];
            p0 += xk * fn0_W1[k * 64 + lane];
            p1 += xk * fn1_W1[k * 64 + lane];
            fs += xk * fs_W1[k * 64 + lane];
        }
        float r0 = 0.f, r1 = 0.f;
        for (int k = 0; k < 64; ++k) {
            float ck = inp[wv][64 + k];
            r0 += ck * fn0_W1[(192 + k) * 64 + lane];
            r1 += ck * fn1_W1[(192 + k) * 64 + lane];
        }
        t1s[wv][lane] = fmaxf(fs + fs_b1[lane], 0.f);
        float sf = 0.f;
        for (int k = 0; k < 64; ++k) sf += t1s[wv][k] * fs_W2[k * 64 + lane];
        sf = fmaxf(sf + fs_b2[lane], 0.f);
        float* pd = perb + (size_t)b * 320;
        pd[lane] = p0; pd[64 + lane] = p1; pd[128 + lane] = r0;
        pd[192 + lane] = r1; pd[256 + lane] = sf;
        if (lane == 0) { qtsA[b] = qs; maskA[b] = mki; }
    }
}

// ---------------- main fused kernel ----------------
#define MFMA(a, bf, c) __builtin_amdgcn_mfma_f32_16x16x32_bf16((a), (bf), (c), 0, 0, 0)

__global__ __launch_bounds__(256, 1) void gkt_main(
    const float* __restrict__ ht, const float* __restrict__ graph,
    const float* __restrict__ ea_w, const float* __restrict__ pred_W,
    const float* __restrict__ pred_b,
    const short* __restrict__ wrepack, const float* __restrict__ biasc,
    const float* __restrict__ ce0g, const float* __restrict__ ce1g,
    const float* __restrict__ perb, const int* __restrict__ qtsA,
    const int* __restrict__ maskA, float* __restrict__ out)
{
    extern __shared__ char smem[];
    // layout: frags 98304 | bias 3072 | pre 1280 | per-wave tiles 4*6912
    short* FRs    = (short*)smem;
    float* s_bias = (float*)(smem + 98304);
    float* s_pre  = (float*)(smem + 101376);
    short* tiles  = (short*)(smem + 102656);

    int tid = threadIdx.x;
    int lane = tid & 63, w = tid >> 6;
    int l15 = lane & 15, q = lane >> 4;
    int bid = blockIdx.x;
    int b = bid >> 2, cb = (bid & 3) << 8;

    short* s_hb = tiles + w * 3456;   // [16][72] bf16 h tile
    short* s_x0 = s_hb + 1152;        // [16][72] bf16
    short* s_x1 = s_x0 + 1152;        // [16][72] bf16

    // ---- block-start staging ----
    {
        const f32x4* src = (const f32x4*)wrepack;  // 6144 x 16B
        f32x4* dst = (f32x4*)FRs;
        for (int i = tid; i < 6144; i += 256) dst[i] = src[i];
        for (int i = tid; i < 768; i += 256) s_bias[i] = biasc[i];
        const float* pd = perb + (size_t)b * 320;
        for (int i = tid; i < 320; i += 256) s_pre[i] = pd[i];
    }
    int qts = qtsA[b];
    int mk  = maskA[b];
    __syncthreads();

    const bf16x8* FR = (const bf16x8*)FRs;
    f32x4 zero4 = {0.f, 0.f, 0.f, 0.f};
    float pb0 = pred_b[0];
    float pw[4];
#pragma unroll
    for (int t = 0; t < 4; ++t) pw[t] = pred_W[t * 16 + l15];

    for (int rt = 0; rt < 4; ++rt) {
        int c0 = cb + w * 64 + rt * 16;
        // direct A-fragment load: lane(l15,q) reads row c0+l15, cols [8q,8q+8) and [32+8q,+8)
        const float* hrow = ht + ((size_t)b * CN + c0 + l15) * 64;
        f32x4 a0 = *(const f32x4*)(hrow + 8 * q);
        f32x4 a1 = *(const f32x4*)(hrow + 8 * q + 4);
        f32x4 a2 = *(const f32x4*)(hrow + 8 * q + 32);
        f32x4 a3 = *(const f32x4*)(hrow + 8 * q + 36);

        if (!mk) {
            f32x4 pwa = *(const f32x4*)(pred_W + 8 * q);
            f32x4 pwb = *(const f32x4*)(pred_W + 8 * q + 4);
            f32x4 pwc = *(const f32x4*)(pred_W + 8 * q + 32);
            f32x4 pwd = *(const f32x4*)(pred_W + 8 * q + 36);
            float part = 0.f;
#pragma unroll
            for (int i = 0; i < 4; ++i)
                part += a0[i] * pwa[i] + a1[i] * pwb[i] + a2[i] * pwc[i] + a3[i] * pwd[i];
            part += __shfl_xor(part, 16);
            part += __shfl_xor(part, 32);
            if (q == 0) out[(size_t)b * CN + c0 + l15] = part + pb0;
            continue;
        }

        bf16x8 hA0, hA1;
#pragma unroll
        for (int j = 0; j < 4; ++j) {
            hA0[j] = f2bf(a0[j]); hA0[4 + j] = f2bf(a1[j]);
            hA1[j] = f2bf(a2[j]); hA1[4 + j] = f2bf(a3[j]);
        }
        // bf16 h tile for GRU z*h term (row l15 fully covered by the 4 q-lanes)
        *(bf16x8*)(s_hb + l15 * 72 + 8 * q) = hA0;
        *(bf16x8*)(s_hb + l15 * 72 + 32 + 8 * q) = hA1;

        // prefetch per-row scalars
        float adjv[4], radjv[4], eav[4];
#pragma unroll
        for (int r = 0; r < 4; ++r) {
            int cr = c0 + q * 4 + r;
            adjv[r]  = graph[(size_t)qts * CN + cr];
            radjv[r] = graph[(size_t)cr * CN + qts];
            eav[r]   = ea_w[cr];
        }
        float cef[8][4];
#pragma unroll
        for (int t = 0; t < 8; ++t) {
            const float* cet = (t < 4) ? ce0g : ce1g;
#pragma unroll
            for (int r = 0; r < 4; ++r) {
                int cr = c0 + q * 4 + r;
                cef[t][r] = cet[(size_t)cr * 64 + (t & 3) * 16 + l15];
            }
        }

        // ---- stage 1: x0 = relu(h@A0 + pre0 + ce0 + b1); x1 likewise ----
#pragma unroll
        for (int t = 0; t < 8; ++t) {
            f32x4 acc = MFMA(hA0, FR[(2 * t) * 64 + lane], zero4);
            acc = MFMA(hA1, FR[(2 * t + 1) * 64 + lane], acc);
            int jl = (t & 3) * 16 + l15;
            float base = s_bias[t * 16 + l15] + ((t < 4) ? s_pre[jl] : s_pre[64 + jl]);
            const float* rwt = (t < 4) ? (s_pre + 128) : (s_pre + 192);
#pragma unroll
            for (int r = 0; r < 4; ++r) {
                int cr = c0 + q * 4 + r;
                float ce = (cr == qts) ? rwt[jl] : cef[t][r];
                float u = fmaxf(acc[r] + base + ce, 0.f);
                if (t < 4) s_x0[(q * 4 + r) * 72 + jl] = f2bf(u);
                else       s_x1[(q * 4 + r) * 72 + jl] = f2bf(u);
            }
        }

        // ---- stage 2: f0/f1; m = adj*f0 + radj*f1 (override at c==qts) ----
        bf16x8 x0A0 = *(const bf16x8*)(s_x0 + l15 * 72 + 8 * q);
        bf16x8 x0A1 = *(const bf16x8*)(s_x0 + l15 * 72 + 32 + 8 * q);
        bf16x8 x1A0 = *(const bf16x8*)(s_x1 + l15 * 72 + 8 * q);
        bf16x8 x1A1 = *(const bf16x8*)(s_x1 + l15 * 72 + 32 + 8 * q);
        float mreg[4][4];
#pragma unroll
        for (int t = 0; t < 4; ++t) {
            f32x4 f0a = MFMA(x0A0, FR[(40 + 2 * t) * 64 + lane], zero4);
            f0a = MFMA(x0A1, FR[(41 + 2 * t) * 64 + lane], f0a);
            f32x4 f1a = MFMA(x1A0, FR[(48 + 2 * t) * 64 + lane], zero4);
            f1a = MFMA(x1A1, FR[(49 + 2 * t) * 64 + lane], f1a);
            int jl = t * 16 + l15;
            float b0 = s_bias[320 + jl], b1 = s_bias[384 + jl];
#pragma unroll
            for (int r = 0; r < 4; ++r) {
                int cr = c0 + q * 4 + r;
                float f0 = fmaxf(f0a[r] + b0, 0.f), f1 = fmaxf(f1a[r] + b1, 0.f);
                float mv = adjv[r] * f0 + radjv[r] * f1;
                if (cr == qts) mv = s_pre[256 + jl];
                mreg[t][r] = mv;
            }
        }
#pragma unroll
        for (int t = 0; t < 4; ++t)
#pragma unroll
            for (int r = 0; r < 4; ++r)
                s_x0[(q * 4 + r) * 72 + t * 16 + l15] = f2bf(mreg[t][r]);

        // ---- stage 3: erase/add gates; m' = m*(1-w*e) + w*a ----
        bf16x8 mA0 = *(const bf16x8*)(s_x0 + l15 * 72 + 8 * q);
        bf16x8 mA1 = *(const bf16x8*)(s_x0 + l15 * 72 + 32 + 8 * q);
#pragma unroll
        for (int t = 0; t < 4; ++t) {
            f32x4 eacc = MFMA(mA0, FR[(56 + 2 * t) * 64 + lane], zero4);
            eacc = MFMA(mA1, FR[(57 + 2 * t) * 64 + lane], eacc);
            f32x4 aacc = MFMA(mA0, FR[(64 + 2 * t) * 64 + lane], zero4);
            aacc = MFMA(mA1, FR[(65 + 2 * t) * 64 + lane], aacc);
            int jl = t * 16 + l15;
            float be = s_bias[448 + jl], ba = s_bias[512 + jl];
#pragma unroll
            for (int r = 0; r < 4; ++r) {
                float eg = sigm(eacc[r] + be);
                float af = tanh_fast(aacc[r] + ba);
                float mp = mreg[t][r] * (1.f - eav[r] * eg) + eav[r] * af;
                s_x1[(q * 4 + r) * 72 + jl] = f2bf(mp);
            }
        }

        // ---- stage 4: GRU gates + prediction ----
        bf16x8 mpA0 = *(const bf16x8*)(s_x1 + l15 * 72 + 8 * q);
        bf16x8 mpA1 = *(const bf16x8*)(s_x1 + l15 * 72 + 32 + 8 * q);
        float rg[4][4], ng[4][4];
#pragma unroll
        for (int t = 0; t < 4; ++t) { // r-gate
            f32x4 gi = MFMA(mpA0, FR[(72 + 2 * t) * 64 + lane], zero4);
            gi = MFMA(mpA1, FR[(73 + 2 * t) * 64 + lane], gi);
            f32x4 gh = MFMA(hA0, FR[(16 + 2 * t) * 64 + lane], zero4);
            gh = MFMA(hA1, FR[(17 + 2 * t) * 64 + lane], gh);
            int jl = t * 16 + l15;
            float bi = s_bias[576 + jl], bh = s_bias[128 + jl];
#pragma unroll
            for (int r = 0; r < 4; ++r)
                rg[t][r] = sigm(gi[r] + bi + gh[r] + bh);
        }
#pragma unroll
        for (int t = 0; t < 4; ++t) { // n-gate
            f32x4 gi = MFMA(mpA0, FR[(88 + 2 * t) * 64 + lane], zero4);
            gi = MFMA(mpA1, FR[(89 + 2 * t) * 64 + lane], gi);
            f32x4 gh = MFMA(hA0, FR[(32 + 2 * t) * 64 + lane], zero4);
            gh = MFMA(hA1, FR[(33 + 2 * t) * 64 + lane], gh);
            int jl = t * 16 + l15;
            float bi = s_bias[704 + jl], bh = s_bias[256 + jl];
#pragma unroll
            for (int r = 0; r < 4; ++r)
                ng[t][r] = tanh_fast(gi[r] + bi + rg[t][r] * (gh[r] + bh));
        }
        float yp[4] = {0.f, 0.f, 0.f, 0.f};
#pragma unroll
        for (int t = 0; t < 4; ++t) { // z-gate + h_next + y partial
            f32x4 gi = MFMA(mpA0, FR[(80 + 2 * t) * 64 + lane], zero4);
            gi = MFMA(mpA1, FR[(81 + 2 * t) * 64 + lane], gi);
            f32x4 gh = MFMA(hA0, FR[(24 + 2 * t) * 64 + lane], zero4);
            gh = MFMA(hA1, FR[(25 + 2 * t) * 64 + lane], gh);
            int jl = t * 16 + l15;
            float bi = s_bias[640 + jl], bh = s_bias[192 + jl];
#pragma unroll
            for (int r = 0; r < 4; ++r) {
                float z = sigm(gi[r] + bi + gh[r] + bh);
                float hval = bf2f(s_hb[(q * 4 + r) * 72 + t * 16 + l15]);
                float hn = (1.f - z) * ng[t][r] + z * hval;
                yp[r] += hn * pw[t];
            }
        }
#pragma unroll
        for (int r = 0; r < 4; ++r) {
            float v = yp[r];
            v += __shfl_xor(v, 1);
            v += __shfl_xor(v, 2);
            v += __shfl_xor(v, 4);
            v += __shfl_xor(v, 8);
            if (l15 == 0) out[(size_t)b * CN + c0 + q * 4 + r] = sigm(v + pb0);
        }
    }
}

extern "C" void kernel_launch(void* const* d_in, const int* in_sizes, int n_in,
                              void* d_out, int out_size, void* d_ws, size_t ws_size,
                              hipStream_t stream) {
    (void)in_sizes; (void)n_in; (void)out_size; (void)ws_size;
    const int*   xt      = (const int*)d_in[0];
    const int*   qt      = (const int*)d_in[1];
    const float* ht      = (const float*)d_in[2];
    const float* graph   = (const float*)d_in[3];
    const float* emb_x   = (const float*)d_in[4];
    const float* emb_c   = (const float*)d_in[5];
    const float* fs_W1   = (const float*)d_in[6];
    const float* fs_b1   = (const float*)d_in[7];
    const float* fs_W2   = (const float*)d_in[8];
    const float* fs_b2   = (const float*)d_in[9];
    const float* fn0_W1  = (const float*)d_in[10];
    const float* fn0_b1  = (const float*)d_in[11];
    const float* fn0_W2  = (const float*)d_in[12];
    const float* fn0_b2  = (const float*)d_in[13];
    const float* fn1_W1  = (const float*)d_in[14];
    const float* fn1_b1  = (const float*)d_in[15];
    const float* fn1_W2  = (const float*)d_in[16];
    const float* fn1_b2  = (const float*)d_in[17];
    const float* ea_w    = (const float*)d_in[18];
    const float* erase_W = (const float*)d_in[19];
    const float* erase_b = (const float*)d_in[20];
    const float* add_W   = (const float*)d_in[21];
    const float* add_b   = (const float*)d_in[22];
    const float* gru_Wih = (const float*)d_in[23];
    const float* gru_bih = (const float*)d_in[24];
    const float* gru_Whh = (const float*)d_in[25];
    const float* gru_bhh = (const float*)d_in[26];
    const float* pred_W  = (const float*)d_in[27];
    const float* pred_b  = (const float*)d_in[28];

    char* ws = (char*)d_ws;
    short* wrepack = (short*)(ws);            // 98304 B
    float* biasc   = (float*)(ws + 98304);    // 3072 B
    float* ce0     = (float*)(ws + 102400);   // 262400 B
    float* ce1     = (float*)(ws + 364800);   // 262400 B
    float* perb    = (float*)(ws + 627200);   // 327680 B
    int*   qtsA    = (int*)(ws + 954880);     // 1024 B
    int*   maskA   = (int*)(ws + 955904);     // 1024 B

    static int attr_set = 0;
    (void)hipFuncSetAttribute((const void*)gkt_main,
                              hipFuncAttributeMaxDynamicSharedMemorySize,
                              SMEM_BYTES);
    (void)attr_set;

    gkt_prep<<<142, 256, 0, stream>>>(
        xt, qt, ht, emb_x, emb_c,
        fs_W1, fs_b1, fs_W2, fs_b2,
        fn0_W1, fn0_b1, fn0_W2, fn0_b2,
        fn1_W1, fn1_b1, fn1_W2, fn1_b2,
        erase_W, erase_b, add_W, add_b,
        gru_Wih, gru_bih, gru_Whh, gru_bhh,
        wrepack, biasc, ce0, ce1, perb, qtsA, maskA);

    gkt_main<<<BN * 4, 256, SMEM_BYTES, stream>>>(
        ht, graph, ea_w, pred_W, pred_b,
        wrepack, biasc, ce0, ce1, perb, qtsA, maskA, (float*)d_out);
}

// Round 3
// 219.797 us; speedup vs baseline: 2.0659x; 1.2910x over previous
//
#include <hip/hip_runtime.h>
#include <hip/hip_bf16.h>

#define CN 1024
#define BN 256
#define SMEM_BYTES 155392

typedef __attribute__((ext_vector_type(4))) float f32x4;
typedef __attribute__((ext_vector_type(8))) short bf16x8;

__device__ __forceinline__ short f2bf(float f) {
    __hip_bfloat16 h = __float2bfloat16(f);
    return *reinterpret_cast<short*>(&h);
}
__device__ __forceinline__ float sigm(float x) {
    return __builtin_amdgcn_rcpf(1.f + __expf(-x));
}
__device__ __forceinline__ float tanh_fast(float x) {
    return 1.f - 2.f * __builtin_amdgcn_rcpf(1.f + __expf(2.f * x));
}

// ---------------- prep kernel ----------------
// blocks [0,14): weight repack, 4 tiles/block (56 col-tiles of concat B 64x896)
// block 14: bias concat. blocks [15,79): per-b tables, wave per b.
__global__ __launch_bounds__(256) void gkt_prep(
    const int* __restrict__ xt, const int* __restrict__ qt,
    const float* __restrict__ ht, const float* __restrict__ emb_x,
    const float* __restrict__ emb_c,
    const float* __restrict__ fs_W1, const float* __restrict__ fs_b1,
    const float* __restrict__ fs_W2, const float* __restrict__ fs_b2,
    const float* __restrict__ fn0_W1, const float* __restrict__ fn0_b1,
    const float* __restrict__ fn0_W2, const float* __restrict__ fn0_b2,
    const float* __restrict__ fn1_W1, const float* __restrict__ fn1_b1,
    const float* __restrict__ fn1_W2, const float* __restrict__ fn1_b2,
    const float* __restrict__ erase_W, const float* __restrict__ erase_b,
    const float* __restrict__ add_W, const float* __restrict__ add_b,
    const float* __restrict__ gru_Wih, const float* __restrict__ gru_bih,
    const float* __restrict__ gru_Whh, const float* __restrict__ gru_bhh,
    short* __restrict__ wrepack, float* __restrict__ biasc,
    float* __restrict__ perb, int* __restrict__ qtsA,
    int* __restrict__ maskA, int* __restrict__ xeA)
{
    int bid = blockIdx.x;
    int tid = threadIdx.x;
    int lane = tid & 63, wv = tid >> 6;
    __shared__ float inp[4][128];
    __shared__ float t1s[4][64];

    if (bid < 14) {
        int t = bid * 4 + wv;           // col-tile in [0,56)
        int colg = t * 16 + (lane & 15);
#pragma unroll
        for (int kh = 0; kh < 2; ++kh) {
            int k0 = kh * 32 + (lane >> 4) * 8;
            short v8[8];
#pragma unroll
            for (int j = 0; j < 8; ++j) {
                int k = k0 + j;
                float v;
                if (colg < 64)       v = fn0_W1[(128 + k) * 64 + colg];
                else if (colg < 128) v = fn1_W1[(128 + k) * 64 + (colg - 64)];
                else if (colg < 320) v = gru_Whh[k * 192 + (colg - 128)];
                else if (colg < 384) v = fn0_W2[k * 64 + (colg - 320)];
                else if (colg < 448) v = fn1_W2[k * 64 + (colg - 384)];
                else if (colg < 512) v = erase_W[k * 64 + (colg - 448)];
                else if (colg < 576) v = add_W[k * 64 + (colg - 512)];
                else if (colg < 768) v = gru_Wih[k * 192 + (colg - 576)];
                else if (colg < 832) v = fn0_W1[(192 + k) * 64 + (colg - 768)];
                else                 v = fn1_W1[(192 + k) * 64 + (colg - 832)];
                v8[j] = f2bf(v);
            }
            short* dst = wrepack + ((size_t)(t * 2 + kh) * 64 + lane) * 8;
#pragma unroll
            for (int j = 0; j < 8; ++j) dst[j] = v8[j];
        }
    } else if (bid == 14) {
        for (int g = tid; g < 768; g += 256) {
            float v;
            if (g < 64)       v = fn0_b1[g];
            else if (g < 128) v = fn1_b1[g - 64];
            else if (g < 320) v = gru_bhh[g - 128];
            else if (g < 384) v = fn0_b2[g - 320];
            else if (g < 448) v = fn1_b2[g - 384];
            else if (g < 512) v = erase_b[g - 448];
            else if (g < 576) v = add_b[g - 512];
            else              v = gru_bih[g - 576];
            biasc[g] = v;
        }
    } else {
        int b = (bid - 15) * 4 + wv;
        int qv = qt[b];
        int mki = (qv != -1);
        int qs = min(max(qv, 0), CN - 1);
        int xe = xt[b];
        float cq = mki ? emb_x[(size_t)xe * 64 + lane]
                       : emb_c[(size_t)CN * 64 + lane];
        inp[wv][lane]      = ht[((size_t)b * CN + qs) * 64 + lane];
        inp[wv][64 + lane] = cq;
        float p0 = 0.f, p1 = 0.f, fs = 0.f;
        for (int k = 0; k < 128; ++k) {
            float xk = inp[wv][k];
            p0 += xk * fn0_W1[k * 64 + lane];
            p1 += xk * fn1_W1[k * 64 + lane];
            fs += xk * fs_W1[k * 64 + lane];
        }
        t1s[wv][lane] = fmaxf(fs + fs_b1[lane], 0.f);
        float sf = 0.f;
        for (int k = 0; k < 64; ++k) sf += t1s[wv][k] * fs_W2[k * 64 + lane];
        sf = fmaxf(sf + fs_b2[lane], 0.f);
        float* pd = perb + (size_t)b * 192;
        pd[lane] = p0; pd[64 + lane] = p1; pd[128 + lane] = sf;
        if (lane == 0) { qtsA[b] = qs; maskA[b] = mki; xeA[b] = xe; }
    }
}

// ---------------- main fused kernel ----------------
#define MFMA(a, bf, c) __builtin_amdgcn_mfma_f32_16x16x32_bf16((a), (bf), (c), 0, 0, 0)

__global__ __launch_bounds__(512, 1) void gkt_main(
    const float* __restrict__ ht, const float* __restrict__ graph,
    const float* __restrict__ ea_w, const float* __restrict__ pred_W,
    const float* __restrict__ pred_b,
    const short* __restrict__ wrepack, const float* __restrict__ biasc,
    const float* __restrict__ perb, const int* __restrict__ qtsA,
    const int* __restrict__ maskA, const int* __restrict__ xeA,
    const float* __restrict__ emb_x, const float* __restrict__ emb_c,
    float* __restrict__ out)
{
    extern __shared__ char smem[];
    short* FRs    = (short*)smem;                  // 114688 B: 112 frags
    float* s_bias = (float*)(smem + 114688);       // 3072 B
    float* s_pre  = (float*)(smem + 117760);       // 768 B: pre0|pre1|sf
    short* tiles  = (short*)(smem + 118528);       // 8 * 4608 B

    int tid = threadIdx.x;
    int lane = tid & 63, w = tid >> 6;
    int l15 = lane & 15, q = lane >> 4;
    int b = blockIdx.x;

    short* s_x0 = tiles + w * 2304;   // [16][72] bf16
    short* s_x1 = s_x0 + 1152;        // [16][72] bf16

    {
        const f32x4* src = (const f32x4*)wrepack;  // 7168 x 16B
        f32x4* dst = (f32x4*)FRs;
        for (int i = tid; i < 7168; i += 512) dst[i] = src[i];
        for (int i = tid; i < 768; i += 512) s_bias[i] = biasc[i];
        const float* pd = perb + (size_t)b * 192;
        if (tid < 192) s_pre[tid] = pd[tid];
    }
    int qts = qtsA[b];
    int mk  = maskA[b];
    int xe  = xeA[b];
    __syncthreads();

    const bf16x8* FR = (const bf16x8*)FRs;
    f32x4 zero4 = {0.f, 0.f, 0.f, 0.f};
    float pb0 = pred_b[0];
    float pw[4];
#pragma unroll
    for (int t = 0; t < 4; ++t) pw[t] = pred_W[t * 16 + l15];

    for (int rt = 0; rt < 8; ++rt) {
        int c0 = w * 128 + rt * 16;
        const float* hrow = ht + ((size_t)b * CN + c0 + l15) * 64;
        f32x4 a0 = *(const f32x4*)(hrow + 8 * q);
        f32x4 a1 = *(const f32x4*)(hrow + 8 * q + 4);
        f32x4 a2 = *(const f32x4*)(hrow + 8 * q + 32);
        f32x4 a3 = *(const f32x4*)(hrow + 8 * q + 36);

        if (!mk) {
            f32x4 pwa = *(const f32x4*)(pred_W + 8 * q);
            f32x4 pwb = *(const f32x4*)(pred_W + 8 * q + 4);
            f32x4 pwc = *(const f32x4*)(pred_W + 8 * q + 32);
            f32x4 pwd = *(const f32x4*)(pred_W + 8 * q + 36);
            float part = 0.f;
#pragma unroll
            for (int i = 0; i < 4; ++i)
                part += a0[i] * pwa[i] + a1[i] * pwb[i] + a2[i] * pwc[i] + a3[i] * pwd[i];
            part += __shfl_xor(part, 16);
            part += __shfl_xor(part, 32);
            if (q == 0) out[(size_t)b * CN + c0 + l15] = part + pb0;
            continue;
        }

        // concept-emb row in A-layout (select res_emb at the query row)
        int rq = c0 + l15;
        const float* ep = (rq == qts) ? (emb_x + (size_t)xe * 64)
                                      : (emb_c + (size_t)rq * 64);
        f32x4 e0 = *(const f32x4*)(ep + 8 * q);
        f32x4 e1 = *(const f32x4*)(ep + 8 * q + 4);
        f32x4 e2 = *(const f32x4*)(ep + 8 * q + 32);
        f32x4 e3 = *(const f32x4*)(ep + 8 * q + 36);

        bf16x8 hA0, hA1, cA0, cA1;
#pragma unroll
        for (int j = 0; j < 4; ++j) {
            hA0[j] = f2bf(a0[j]); hA0[4 + j] = f2bf(a1[j]);
            hA1[j] = f2bf(a2[j]); hA1[4 + j] = f2bf(a3[j]);
            cA0[j] = f2bf(e0[j]); cA0[4 + j] = f2bf(e1[j]);
            cA1[j] = f2bf(e2[j]); cA1[4 + j] = f2bf(e3[j]);
        }

        // per-row scalars + h rows in D-layout (for GRU z*h) -- issue early
        float adjv[4], radjv[4], eav[4];
#pragma unroll
        for (int r = 0; r < 4; ++r) {
            int cr = c0 + q * 4 + r;
            adjv[r]  = graph[(size_t)qts * CN + cr];
            radjv[r] = graph[(size_t)cr * CN + qts];
            eav[r]   = ea_w[cr];
        }
        float hv[4][4];
#pragma unroll
        for (int t = 0; t < 4; ++t)
#pragma unroll
            for (int r = 0; r < 4; ++r)
                hv[t][r] = ht[((size_t)b * CN + c0 + q * 4 + r) * 64 + t * 16 + l15];

        // ---- stage 1: x = relu(h@W1h + ce@W1c + pre + b1) for fn0 (t<4), fn1 (t>=4)
#pragma unroll
        for (int t = 0; t < 8; ++t) {
            f32x4 acc = MFMA(hA0, FR[(2 * t) * 64 + lane], zero4);
            acc = MFMA(hA1, FR[(2 * t + 1) * 64 + lane], acc);
            acc = MFMA(cA0, FR[(96 + 2 * t) * 64 + lane], acc);
            acc = MFMA(cA1, FR[(97 + 2 * t) * 64 + lane], acc);
            int jl = (t & 3) * 16 + l15;
            float base = s_bias[t * 16 + l15] + ((t < 4) ? s_pre[jl] : s_pre[64 + jl]);
#pragma unroll
            for (int r = 0; r < 4; ++r) {
                float u = fmaxf(acc[r] + base, 0.f);
                if (t < 4) s_x0[(q * 4 + r) * 72 + jl] = f2bf(u);
                else       s_x1[(q * 4 + r) * 72 + jl] = f2bf(u);
            }
        }

        // ---- stage 2: f0/f1; m = adj*f0 + radj*f1 (override at c==qts) ----
        bf16x8 x0A0 = *(const bf16x8*)(s_x0 + l15 * 72 + 8 * q);
        bf16x8 x0A1 = *(const bf16x8*)(s_x0 + l15 * 72 + 32 + 8 * q);
        bf16x8 x1A0 = *(const bf16x8*)(s_x1 + l15 * 72 + 8 * q);
        bf16x8 x1A1 = *(const bf16x8*)(s_x1 + l15 * 72 + 32 + 8 * q);
        float mreg[4][4];
#pragma unroll
        for (int t = 0; t < 4; ++t) {
            f32x4 f0a = MFMA(x0A0, FR[(40 + 2 * t) * 64 + lane], zero4);
            f0a = MFMA(x0A1, FR[(41 + 2 * t) * 64 + lane], f0a);
            f32x4 f1a = MFMA(x1A0, FR[(48 + 2 * t) * 64 + lane], zero4);
            f1a = MFMA(x1A1, FR[(49 + 2 * t) * 64 + lane], f1a);
            int jl = t * 16 + l15;
            float b0 = s_bias[320 + jl], b1 = s_bias[384 + jl];
#pragma unroll
            for (int r = 0; r < 4; ++r) {
                int cr = c0 + q * 4 + r;
                float f0 = fmaxf(f0a[r] + b0, 0.f), f1 = fmaxf(f1a[r] + b1, 0.f);
                float mv = adjv[r] * f0 + radjv[r] * f1;
                if (cr == qts) mv = s_pre[128 + jl];
                mreg[t][r] = mv;
            }
        }
#pragma unroll
        for (int t = 0; t < 4; ++t)
#pragma unroll
            for (int r = 0; r < 4; ++r)
                s_x0[(q * 4 + r) * 72 + t * 16 + l15] = f2bf(mreg[t][r]);

        // ---- stage 3: erase/add gates; m' = m*(1-w*e) + w*a ----
        bf16x8 mA0 = *(const bf16x8*)(s_x0 + l15 * 72 + 8 * q);
        bf16x8 mA1 = *(const bf16x8*)(s_x0 + l15 * 72 + 32 + 8 * q);
#pragma unroll
        for (int t = 0; t < 4; ++t) {
            f32x4 eacc = MFMA(mA0, FR[(56 + 2 * t) * 64 + lane], zero4);
            eacc = MFMA(mA1, FR[(57 + 2 * t) * 64 + lane], eacc);
            f32x4 aacc = MFMA(mA0, FR[(64 + 2 * t) * 64 + lane], zero4);
            aacc = MFMA(mA1, FR[(65 + 2 * t) * 64 + lane], aacc);
            int jl = t * 16 + l15;
            float be = s_bias[448 + jl], ba = s_bias[512 + jl];
#pragma unroll
            for (int r = 0; r < 4; ++r) {
                float eg = sigm(eacc[r] + be);
                float af = tanh_fast(aacc[r] + ba);
                float mp = mreg[t][r] * (1.f - eav[r] * eg) + eav[r] * af;
                s_x1[(q * 4 + r) * 72 + jl] = f2bf(mp);
            }
        }

        // ---- stage 4: GRU gates + prediction ----
        bf16x8 mpA0 = *(const bf16x8*)(s_x1 + l15 * 72 + 8 * q);
        bf16x8 mpA1 = *(const bf16x8*)(s_x1 + l15 * 72 + 32 + 8 * q);
        float rg[4][4], ng[4][4];
#pragma unroll
        for (int t = 0; t < 4; ++t) { // r-gate
            f32x4 gi = MFMA(mpA0, FR[(72 + 2 * t) * 64 + lane], zero4);
            gi = MFMA(mpA1, FR[(73 + 2 * t) * 64 + lane], gi);
            f32x4 gh = MFMA(hA0, FR[(16 + 2 * t) * 64 + lane], zero4);
            gh = MFMA(hA1, FR[(17 + 2 * t) * 64 + lane], gh);
            int jl = t * 16 + l15;
            float bi = s_bias[576 + jl], bh = s_bias[128 + jl];
#pragma unroll
            for (int r = 0; r < 4; ++r)
                rg[t][r] = sigm(gi[r] + bi + gh[r] + bh);
        }
#pragma unroll
        for (int t = 0; t < 4; ++t) { // n-gate
            f32x4 gi = MFMA(mpA0, FR[(88 + 2 * t) * 64 + lane], zero4);
            gi = MFMA(mpA1, FR[(89 + 2 * t) * 64 + lane], gi);
            f32x4 gh = MFMA(hA0, FR[(32 + 2 * t) * 64 + lane], zero4);
            gh = MFMA(hA1, FR[(33 + 2 * t) * 64 + lane], gh);
            int jl = t * 16 + l15;
            float bi = s_bias[704 + jl], bh = s_bias[256 + jl];
#pragma unroll
            for (int r = 0; r < 4; ++r)
                ng[t][r] = tanh_fast(gi[r] + bi + rg[t][r] * (gh[r] + bh));
        }
        float yp[4] = {0.f, 0.f, 0.f, 0.f};
#pragma unroll
        for (int t = 0; t < 4; ++t) { // z-gate + h_next + y partial
            f32x4 gi = MFMA(mpA0, FR[(80 + 2 * t) * 64 + lane], zero4);
            gi = MFMA(mpA1, FR[(81 + 2 * t) * 64 + lane], gi);
            f32x4 gh = MFMA(hA0, FR[(24 + 2 * t) * 64 + lane], zero4);
            gh = MFMA(hA1, FR[(25 + 2 * t) * 64 + lane], gh);
            int jl = t * 16 + l15;
            float bi = s_bias[640 + jl], bh = s_bias[192 + jl];
#pragma unroll
            for (int r = 0; r < 4; ++r) {
                float z = sigm(gi[r] + bi + gh[r] + bh);
                float hn = (1.f - z) * ng[t][r] + z * hv[t][r];
                yp[r] += hn * pw[t];
            }
        }
#pragma unroll
        for (int r = 0; r < 4; ++r) {
            float v = yp[r];
            v += __shfl_xor(v, 1);
            v += __shfl_xor(v, 2);
            v += __shfl_xor(v, 4);
            v += __shfl_xor(v, 8);
            if (l15 == 0) out[(size_t)b * CN + c0 + q * 4 + r] = sigm(v + pb0);
        }
    }
}

extern "C" void kernel_launch(void* const* d_in, const int* in_sizes, int n_in,
                              void* d_out, int out_size, void* d_ws, size_t ws_size,
                              hipStream_t stream) {
    (void)in_sizes; (void)n_in; (void)out_size; (void)ws_size;
    const int*   xt      = (const int*)d_in[0];
    const int*   qt      = (const int*)d_in[1];
    const float* ht      = (const float*)d_in[2];
    const float* graph   = (const float*)d_in[3];
    const float* emb_x   = (const float*)d_in[4];
    const float* emb_c   = (const float*)d_in[5];
    const float* fs_W1   = (const float*)d_in[6];
    const float* fs_b1   = (const float*)d_in[7];
    const float* fs_W2   = (const float*)d_in[8];
    const float* fs_b2   = (const float*)d_in[9];
    const float* fn0_W1  = (const float*)d_in[10];
    const float* fn0_b1  = (const float*)d_in[11];
    const float* fn0_W2  = (const float*)d_in[12];
    const float* fn0_b2  = (const float*)d_in[13];
    const float* fn1_W1  = (const float*)d_in[14];
    const float* fn1_b1  = (const float*)d_in[15];
    const float* fn1_W2  = (const float*)d_in[16];
    const float* fn1_b2  = (const float*)d_in[17];
    const float* ea_w    = (const float*)d_in[18];
    const float* erase_W = (const float*)d_in[19];
    const float* erase_b = (const float*)d_in[20];
    const float* add_W   = (const float*)d_in[21];
    const float* add_b   = (const float*)d_in[22];
    const float* gru_Wih = (const float*)d_in[23];
    const float* gru_bih = (const float*)d_in[24];
    const float* gru_Whh = (const float*)d_in[25];
    const float* gru_bhh = (const float*)d_in[26];
    const float* pred_W  = (const float*)d_in[27];
    const float* pred_b  = (const float*)d_in[28];

    char* ws = (char*)d_ws;
    short* wrepack = (short*)(ws);            // 114688 B
    float* biasc   = (float*)(ws + 114688);   // 3072 B
    float* perb    = (float*)(ws + 117760);   // 196608 B
    int*   qtsA    = (int*)(ws + 314368);     // 1024 B
    int*   maskA   = (int*)(ws + 315392);     // 1024 B
    int*   xeA     = (int*)(ws + 316416);     // 1024 B

    (void)hipFuncSetAttribute((const void*)gkt_main,
                              hipFuncAttributeMaxDynamicSharedMemorySize,
                              SMEM_BYTES);

    gkt_prep<<<79, 256, 0, stream>>>(
        xt, qt, ht, emb_x, emb_c,
        fs_W1, fs_b1, fs_W2, fs_b2,
        fn0_W1, fn0_b1, fn0_W2, fn0_b2,
        fn1_W1, fn1_b1, fn1_W2, fn1_b2,
        erase_W, erase_b, add_W, add_b,
        gru_Wih, gru_bih, gru_Whh, gru_bhh,
        wrepack, biasc, perb, qtsA, maskA, xeA);

    gkt_main<<<BN, 512, SMEM_BYTES, stream>>>(
        ht, graph, ea_w, pred_W, pred_b,
        wrepack, biasc, perb, qtsA, maskA, xeA,
        emb_x, emb_c, (float*)d_out);
}